// Round 4
// baseline (1301.795 us; speedup 1.0000x reference)
//
#include <hip/hip_runtime.h>
#include <math.h>

#define V 100000
#define D 128
#define A 64
#define LVLS 3
#define NN 20000
#define KK 16

// out[dst] = W[src] @ Wmat(128x64) + bias
// Wave-PAIR split-K: wave hw in {0,1} holds d-half hw*64..hw*64+63 of Wmat in
// 64 VGPRs (loaded once). Pair stages a 16-row A-tile in LDS (coalesced
// float2), each wave reduces its half via wave-uniform ds_read_b128
// broadcasts, halves summed through an LDS exchange. ~110 VGPRs -> 4 waves/SIMD.
__global__ __launch_bounds__(256, 4)
void proj_kernel(const float* __restrict__ Wsrc, const float* __restrict__ Wmat,
                 const float* __restrict__ bias, const int* __restrict__ idx,
                 int dst_from_idx, int nrows, float* __restrict__ outp) {
    __shared__ float As[2 * 16 * D];    // 16 KB: one 16-row tile per wave-pair
    __shared__ float Xch[2 * 16 * A];   // 8 KB: partial-acc exchange
    int lane = threadIdx.x & 63, wave = threadIdx.x >> 6;
    int pair = wave >> 1, hw = wave & 1;
    float* Aw = As + pair * 16 * D;
    float* Xw = Xch + pair * 16 * A;

    float w[64];
#pragma unroll
    for (int j = 0; j < 64; ++j) w[j] = Wmat[(hw * 64 + j) * A + lane];
    float b = (hw == 0 && bias) ? bias[lane] : 0.f;

    int ntiles = (nrows + 15) >> 4;
    for (int bt = blockIdx.x * 2; bt < ntiles; bt += gridDim.x * 2) {
        int tp = bt + pair;                 // may exceed ntiles-1: work clamped
        int r0 = tp << 4;
#pragma unroll
        for (int i = 0; i < 8; ++i) {       // this wave stages rows hw*8..hw*8+7
            int rl = hw * 8 + i;
            int r = r0 + rl; int rr = r < nrows ? r : nrows - 1;
            int src = idx ? idx[rr] : rr;
            float2 v = *(const float2*)(Wsrc + (size_t)src * D + 2 * lane);
            *(float2*)(Aw + rl * D + 2 * lane) = v;
        }
        __syncthreads();

        float acc[16];
        const float* Ah = Aw + hw * 64;
#pragma unroll 2
        for (int r = 0; r < 16; ++r) {
            const float* ar = Ah + r * D;
            float a0 = b, a1 = 0.f, a2 = 0.f, a3 = 0.f;
#pragma unroll
            for (int dc = 0; dc < 64; dc += 16) {
                float4 x0 = *(const float4*)(ar + dc);
                float4 x1 = *(const float4*)(ar + dc + 4);
                float4 x2 = *(const float4*)(ar + dc + 8);
                float4 x3 = *(const float4*)(ar + dc + 12);
                a0 = fmaf(x0.x, w[dc + 0], a0);  a0 = fmaf(x0.y, w[dc + 1], a0);
                a0 = fmaf(x0.z, w[dc + 2], a0);  a0 = fmaf(x0.w, w[dc + 3], a0);
                a1 = fmaf(x1.x, w[dc + 4], a1);  a1 = fmaf(x1.y, w[dc + 5], a1);
                a1 = fmaf(x1.z, w[dc + 6], a1);  a1 = fmaf(x1.w, w[dc + 7], a1);
                a2 = fmaf(x2.x, w[dc + 8], a2);  a2 = fmaf(x2.y, w[dc + 9], a2);
                a2 = fmaf(x2.z, w[dc + 10], a2); a2 = fmaf(x2.w, w[dc + 11], a2);
                a3 = fmaf(x3.x, w[dc + 12], a3); a3 = fmaf(x3.y, w[dc + 13], a3);
                a3 = fmaf(x3.z, w[dc + 14], a3); a3 = fmaf(x3.w, w[dc + 15], a3);
            }
            acc[r] = (a0 + a1) + (a2 + a3);
        }

        if (hw == 1) {
#pragma unroll
            for (int r = 0; r < 16; ++r) Xw[r * A + lane] = acc[r];
        }
        __syncthreads();
        if (hw == 0) {
#pragma unroll
            for (int r = 0; r < 16; ++r) {
                int rr = r0 + r;
                if (rr < nrows) {
                    int src = idx ? idx[rr] : rr;
                    int dst = dst_from_idx ? src : rr;
                    outp[(size_t)dst * A + lane] = acc[r] + Xw[r * A + lane];
                }
            }
        }
        __syncthreads();   // Xch/As consumed; safe to overwrite next iteration
    }
}

// One wave per node. Phase 1: lane (k16 = lane&15, q = lane>>4) computes the
// q-th 16-dim partial of pre[k]; 2 shuffles reduce over q. 16-group softmax
// butterflies. Phase 2: per-lane float2 over D with shfl-broadcast att/nb.
__global__ __launch_bounds__(256)
void attn_kernel(const float* __restrict__ Wc, const float* __restrict__ proj,
                 const float* __restrict__ nodeproj, const int* __restrict__ neigh,
                 const float* __restrict__ maskp, const float* __restrict__ weightp,
                 const float* __restrict__ v_att, float* __restrict__ tmp) {
    int lane = threadIdx.x & 63;
    int n = blockIdx.x * 4 + (threadIdx.x >> 6);
    int k16 = lane & 15, q = lane >> 4;

    int   nbk = neigh[n * KK + k16];
    float wv  = weightp[n * KK + k16];
    float mk  = maskp[n * KK + k16];

    const float* npr = nodeproj + (size_t)n * A + q * 16;
    const float* var = v_att + q * 16;
    const float* pr  = proj + (size_t)nbk * A + q * 16;

    float part = 0.f;
#pragma unroll
    for (int j = 0; j < 16; j += 4) {
        float4 npv = *(const float4*)(npr + j);
        float4 vav = *(const float4*)(var + j);
        float4 pv  = *(const float4*)(pr + j);
        float x;
        x = npv.x + pv.x; x = fmaxf(x, 0.01f * x); part = fmaf(x, vav.x, part);
        x = npv.y + pv.y; x = fmaxf(x, 0.01f * x); part = fmaf(x, vav.y, part);
        x = npv.z + pv.z; x = fmaxf(x, 0.01f * x); part = fmaf(x, vav.z, part);
        x = npv.w + pv.w; x = fmaxf(x, 0.01f * x); part = fmaf(x, vav.w, part);
    }
    part += __shfl_xor(part, 16);
    part += __shfl_xor(part, 32);
    float pre = part + mk;

    float mp = pre, mw = wv;
#pragma unroll
    for (int off = 8; off >= 1; off >>= 1) {
        mp = fmaxf(mp, __shfl_xor(mp, off));
        mw = fmaxf(mw, __shfl_xor(mw, off));
    }
    float ep = __expf(pre - mp), ew = __expf(wv - mw);
    float sp = ep, sw = ew;
#pragma unroll
    for (int off = 8; off >= 1; off >>= 1) {
        sp += __shfl_xor(sp, off);
        sw += __shfl_xor(sw, off);
    }
    float att = (ep / sp) * (ew / sw);

    float ax = 0.f, ay = 0.f;
#pragma unroll
    for (int k = 0; k < KK; ++k) {
        int nb   = __shfl(nbk, k);
        float ak = __shfl(att, k);
        float2 e = *(const float2*)&Wc[(size_t)nb * D + 2 * lane];
        ax = fmaf(e.x, ak, ax); ay = fmaf(e.y, ak, ay);
    }
    float2 o; o.x = ax; o.y = ay;
    *(float2*)&tmp[(size_t)n * D + 2 * lane] = o;
}

__global__ void amax_kernel(const int* __restrict__ nodes_l, int* __restrict__ claim, int n) {
    int i = blockIdx.x * 256 + threadIdx.x;
    if (i < n) atomicMax(&claim[nodes_l[i]], i);
}

// last-occurrence-wins scatter (matches numpy fancy-assign semantics)
__global__ void scatter_kernel(const int* __restrict__ nodes_l, const int* __restrict__ claim,
                               const float* __restrict__ tmp, float* __restrict__ out, int n) {
    int tid = blockIdx.x * 256 + threadIdx.x;
    int nn = tid >> 7, d = tid & 127;
    if (nn < n) {
        int v = nodes_l[nn];
        if (claim[v] == nn) out[(size_t)v * D + d] = tmp[(size_t)nn * D + d];
    }
}

static inline int proj_blocks(int nrows) {
    int ntiles = (nrows + 15) >> 4;
    int blocks = (ntiles + 1) / 2;
    return blocks > 1024 ? 1024 : blocks;
}

extern "C" void kernel_launch(void* const* d_in, const int* in_sizes, int n_in,
                              void* d_out, int out_size, void* d_ws, size_t ws_size,
                              hipStream_t stream) {
    const float* Leaf    = (const float*)d_in[0];
    const int*   nodes   = (const int*)d_in[1];
    const int*   neigh   = (const int*)d_in[2];
    const float* masks   = (const float*)d_in[3];
    const float* weights = (const float*)d_in[4];
    const float* Watt    = (const float*)d_in[5];
    const float* batt    = (const float*)d_in[6];
    const float* vatt    = (const float*)d_in[7];
    float* out = (float*)d_out;

    char* ws = (char*)d_ws;
    float* proj     = (float*)ws;                                   // V*A
    float* nodeproj = (float*)(ws + (size_t)V * A * 4);             // L*N*A
    float* tmp      = (float*)(ws + (size_t)V * A * 4 + (size_t)LVLS * NN * A * 4);  // N*D
    int*   claim    = (int*)(ws + (size_t)V * A * 4 + (size_t)LVLS * NN * A * 4
                                + (size_t)NN * D * 4);              // V ints

    hipMemcpyAsync(out, Leaf, (size_t)V * D * sizeof(float), hipMemcpyDeviceToDevice, stream);

    // node-half projection for all levels (ORIGINAL Leaf_emb rows)
    proj_kernel<<<proj_blocks(LVLS * NN), 256, 0, stream>>>(
        Leaf, Watt, batt, nodes, 0, LVLS * NN, nodeproj);
    // neighbor-half projection for all V rows of current W_tmp
    proj_kernel<<<proj_blocks(V), 256, 0, stream>>>(
        out, Watt + D * A, nullptr, nullptr, 0, V, proj);

    for (int l = 0; l < LVLS; ++l) {
        const int* nodes_l = nodes + l * NN;
        attn_kernel<<<NN / 4, 256, 0, stream>>>(out, proj, nodeproj + (size_t)l * NN * A,
                                                neigh + (size_t)l * NN * KK,
                                                masks + (size_t)l * NN * KK,
                                                weights + (size_t)l * NN * KK, vatt, tmp);
        hipMemsetAsync(claim, 0xFF, (size_t)V * sizeof(int), stream);   // -1
        amax_kernel<<<(NN + 255) / 256, 256, 0, stream>>>(nodes_l, claim, NN);
        scatter_kernel<<<(NN * D + 255) / 256, 256, 0, stream>>>(nodes_l, claim, tmp, out, NN);
        if (l + 1 < LVLS)  // refresh proj only for rows just rewritten
            proj_kernel<<<proj_blocks(NN), 256, 0, stream>>>(
                out, Watt + D * A, nullptr, nodes_l, 1, NN, proj);
    }
}

// Round 5
// 336.502 us; speedup vs baseline: 3.8686x; 3.8686x over previous
//
#include <hip/hip_runtime.h>
#include <math.h>

#define V 100000
#define D 128
#define A 64
#define LVLS 3
#define NN 20000
#define KK 16
#define BK 32
#define ASTRIDE 34   // 32 + 2 pad -> 2-way LDS aliasing only (free)
#define BSTRIDE 68   // 64 + 4 pad

// out[dst] = W[src] @ Wmat(128x64) + bias   (src = idx?idx[j]:j)
// Register-tiled SGEMM: 128x64 block tile, 8x4 microtile/thread, K chunked 32.
// All accumulators statically indexed (NO dynamic-index arrays -> no scratch).
__global__ __launch_bounds__(256, 2)
void proj_kernel(const float* __restrict__ Wsrc, const float* __restrict__ Wmat,
                 const float* __restrict__ bias, const int* __restrict__ idx,
                 int dst_from_idx, int nrows, float* __restrict__ outp) {
    __shared__ float As[128 * ASTRIDE];  // 17.4 KB
    __shared__ float Bs[BK * BSTRIDE];   // 8.7 KB
    int t = threadIdx.x;
    int tx = t & 15, ty = t >> 4;        // tx: 4-col group, ty: 8-row group
    int r0 = blockIdx.x * 128;

    // staging source pointers (4 rows per thread, koff = (t&7)*4)
    const float* srcp[4];
#pragma unroll
    for (int jj = 0; jj < 4; ++jj) {
        int r = r0 + (t >> 3) + 32 * jj;
        int rr = r < nrows ? r : nrows - 1;
        int s = idx ? idx[rr] : rr;
        srcp[jj] = Wsrc + (size_t)s * D + ((t & 7) << 2);
    }

    float4 bv = make_float4(0.f, 0.f, 0.f, 0.f);
    if (bias) bv = *(const float4*)(bias + 4 * tx);
    float acc[8][4];
#pragma unroll
    for (int i = 0; i < 8; ++i) {
        acc[i][0] = bv.x; acc[i][1] = bv.y; acc[i][2] = bv.z; acc[i][3] = bv.w;
    }

    for (int k0 = 0; k0 < D; k0 += BK) {
#pragma unroll
        for (int jj = 0; jj < 4; ++jj) {
            float4 v = *(const float4*)(srcp[jj] + k0);
            *(float4*)&As[((t >> 3) + 32 * jj) * ASTRIDE + ((t & 7) << 2)] = v;
        }
#pragma unroll
        for (int ss = 0; ss < 2; ++ss) {
            int s = t + 256 * ss;
            int kB = s >> 4, c4 = (s & 15) << 2;
            *(float4*)&Bs[kB * BSTRIDE + c4] =
                *(const float4*)(Wmat + (size_t)(k0 + kB) * A + c4);
        }
        __syncthreads();
#pragma unroll
        for (int kc = 0; kc < BK; kc += 4) {
            float4 b0 = *(const float4*)&Bs[(kc + 0) * BSTRIDE + 4 * tx];
            float4 b1 = *(const float4*)&Bs[(kc + 1) * BSTRIDE + 4 * tx];
            float4 b2 = *(const float4*)&Bs[(kc + 2) * BSTRIDE + 4 * tx];
            float4 b3 = *(const float4*)&Bs[(kc + 3) * BSTRIDE + 4 * tx];
#pragma unroll
            for (int i = 0; i < 8; ++i) {
                float4 a = *(const float4*)&As[(8 * ty + i) * ASTRIDE + kc];
                acc[i][0] = fmaf(a.x, b0.x, acc[i][0]);
                acc[i][0] = fmaf(a.y, b1.x, acc[i][0]);
                acc[i][0] = fmaf(a.z, b2.x, acc[i][0]);
                acc[i][0] = fmaf(a.w, b3.x, acc[i][0]);
                acc[i][1] = fmaf(a.x, b0.y, acc[i][1]);
                acc[i][1] = fmaf(a.y, b1.y, acc[i][1]);
                acc[i][1] = fmaf(a.z, b2.y, acc[i][1]);
                acc[i][1] = fmaf(a.w, b3.y, acc[i][1]);
                acc[i][2] = fmaf(a.x, b0.z, acc[i][2]);
                acc[i][2] = fmaf(a.y, b1.z, acc[i][2]);
                acc[i][2] = fmaf(a.z, b2.z, acc[i][2]);
                acc[i][2] = fmaf(a.w, b3.z, acc[i][2]);
                acc[i][3] = fmaf(a.x, b0.w, acc[i][3]);
                acc[i][3] = fmaf(a.y, b1.w, acc[i][3]);
                acc[i][3] = fmaf(a.z, b2.w, acc[i][3]);
                acc[i][3] = fmaf(a.w, b3.w, acc[i][3]);
            }
        }
        __syncthreads();
    }

#pragma unroll
    for (int i = 0; i < 8; ++i) {
        int gr = r0 + 8 * ty + i;
        if (gr < nrows) {
            int s = idx ? idx[gr] : gr;
            int dst = dst_from_idx ? s : gr;
            float4 o = make_float4(acc[i][0], acc[i][1], acc[i][2], acc[i][3]);
            *(float4*)(outp + (size_t)dst * A + 4 * tx) = o;
        }
    }
}

// One wave per node (unchanged from R3 — passed, ~75 us/level; next target).
__global__ __launch_bounds__(256)
void attn_kernel(const float* __restrict__ Wc, const float* __restrict__ proj,
                 const float* __restrict__ nodeproj, const int* __restrict__ neigh,
                 const float* __restrict__ maskp, const float* __restrict__ weightp,
                 const float* __restrict__ v_att, float* __restrict__ tmp) {
    int lane = threadIdx.x & 63;
    int n = blockIdx.x * 4 + (threadIdx.x >> 6);
    int k16 = lane & 15, q = lane >> 4;

    int   nbk = neigh[n * KK + k16];
    float wv  = weightp[n * KK + k16];
    float mk  = maskp[n * KK + k16];

    const float* npr = nodeproj + (size_t)n * A + q * 16;
    const float* var = v_att + q * 16;
    const float* pr  = proj + (size_t)nbk * A + q * 16;

    float part = 0.f;
#pragma unroll
    for (int j = 0; j < 16; j += 4) {
        float4 npv = *(const float4*)(npr + j);
        float4 vav = *(const float4*)(var + j);
        float4 pv  = *(const float4*)(pr + j);
        float x;
        x = npv.x + pv.x; x = fmaxf(x, 0.01f * x); part = fmaf(x, vav.x, part);
        x = npv.y + pv.y; x = fmaxf(x, 0.01f * x); part = fmaf(x, vav.y, part);
        x = npv.z + pv.z; x = fmaxf(x, 0.01f * x); part = fmaf(x, vav.z, part);
        x = npv.w + pv.w; x = fmaxf(x, 0.01f * x); part = fmaf(x, vav.w, part);
    }
    part += __shfl_xor(part, 16);
    part += __shfl_xor(part, 32);
    float pre = part + mk;

    float mp = pre, mw = wv;
#pragma unroll
    for (int off = 8; off >= 1; off >>= 1) {
        mp = fmaxf(mp, __shfl_xor(mp, off));
        mw = fmaxf(mw, __shfl_xor(mw, off));
    }
    float ep = __expf(pre - mp), ew = __expf(wv - mw);
    float sp = ep, sw = ew;
#pragma unroll
    for (int off = 8; off >= 1; off >>= 1) {
        sp += __shfl_xor(sp, off);
        sw += __shfl_xor(sw, off);
    }
    float att = (ep / sp) * (ew / sw);

    float ax = 0.f, ay = 0.f;
#pragma unroll
    for (int k = 0; k < KK; ++k) {
        int nb   = __shfl(nbk, k);
        float ak = __shfl(att, k);
        float2 e = *(const float2*)&Wc[(size_t)nb * D + 2 * lane];
        ax = fmaf(e.x, ak, ax); ay = fmaf(e.y, ak, ay);
    }
    float2 o; o.x = ax; o.y = ay;
    *(float2*)&tmp[(size_t)n * D + 2 * lane] = o;
}

// claims for ALL levels in one pass (depends only on nodes input)
__global__ void amax3_kernel(const int* __restrict__ nodes, int* __restrict__ claims, int total) {
    int i = blockIdx.x * 256 + threadIdx.x;
    if (i < total) {
        int lvl = i / NN, pos = i - lvl * NN;
        atomicMax(&claims[(size_t)lvl * V + nodes[i]], pos);
    }
}

// last-occurrence-wins scatter (matches numpy fancy-assign semantics)
__global__ void scatter_kernel(const int* __restrict__ nodes_l, const int* __restrict__ claim,
                               const float* __restrict__ tmp, float* __restrict__ out, int n) {
    int tid = blockIdx.x * 256 + threadIdx.x;
    int nn = tid >> 7, d = tid & 127;
    if (nn < n) {
        int v = nodes_l[nn];
        if (claim[v] == nn) out[(size_t)v * D + d] = tmp[(size_t)nn * D + d];
    }
}

extern "C" void kernel_launch(void* const* d_in, const int* in_sizes, int n_in,
                              void* d_out, int out_size, void* d_ws, size_t ws_size,
                              hipStream_t stream) {
    const float* Leaf    = (const float*)d_in[0];
    const int*   nodes   = (const int*)d_in[1];
    const int*   neigh   = (const int*)d_in[2];
    const float* masks   = (const float*)d_in[3];
    const float* weights = (const float*)d_in[4];
    const float* Watt    = (const float*)d_in[5];
    const float* batt    = (const float*)d_in[6];
    const float* vatt    = (const float*)d_in[7];
    float* out = (float*)d_out;

    char* ws = (char*)d_ws;
    float* proj     = (float*)ws;                                              // V*A
    float* nodeproj = (float*)(ws + (size_t)V * A * 4);                        // L*N*A
    float* tmp      = (float*)(ws + (size_t)(V * A + LVLS * NN * A) * 4);      // N*D
    int*   claims   = (int*)(ws + (size_t)(V * A + LVLS * NN * A + NN * D) * 4); // 3*V

    hipMemcpyAsync(out, Leaf, (size_t)V * D * sizeof(float), hipMemcpyDeviceToDevice, stream);
    hipMemsetAsync(claims, 0xFF, (size_t)LVLS * V * sizeof(int), stream);      // -1

    // node-half projection for all levels (ORIGINAL Leaf_emb rows)
    proj_kernel<<<(LVLS * NN + 127) / 128, 256, 0, stream>>>(
        Leaf, Watt, batt, nodes, 0, LVLS * NN, nodeproj);
    // neighbor-half projection for all V rows of current W_tmp
    proj_kernel<<<(V + 127) / 128, 256, 0, stream>>>(
        out, Watt + D * A, nullptr, nullptr, 0, V, proj);
    // winner claims for all levels at once
    amax3_kernel<<<(LVLS * NN + 255) / 256, 256, 0, stream>>>(nodes, claims, LVLS * NN);

    for (int l = 0; l < LVLS; ++l) {
        const int* nodes_l = nodes + l * NN;
        attn_kernel<<<NN / 4, 256, 0, stream>>>(out, proj, nodeproj + (size_t)l * NN * A,
                                                neigh + (size_t)l * NN * KK,
                                                masks + (size_t)l * NN * KK,
                                                weights + (size_t)l * NN * KK, vatt, tmp);
        scatter_kernel<<<(NN * D + 255) / 256, 256, 0, stream>>>(
            nodes_l, claims + (size_t)l * V, tmp, out, NN);
        if (l + 1 < LVLS)  // refresh proj only for rows just rewritten
            proj_kernel<<<(NN + 127) / 128, 256, 0, stream>>>(
                out, Watt + D * A, nullptr, nodes_l, 1, NN, proj);
    }
}